// Round 5
// baseline (507.909 us; speedup 1.0000x reference)
//
#include <hip/hip_runtime.h>
#include <hip/hip_fp16.h>

#define N_BATCH 8
#define LQ_     2500
#define DM_     256
#define NH_     8
#define NL_     4
#define NP_     8
#define DH_     32
#define LEN_IN_ 14960
#define KDIM    256

#define MV_   119680   // N_BATCH * LEN_IN_
#define MQ_   20000    // N_BATCH * LQ_
#define NBMV  935      // MV_/128 row panels (exact)
#define NBMQ  157      // ceil(MQ_/128) row panels
#define NVB   1872     // value-GEMM block slots (8 xcd * 117 * 2, 2 idle)
#define NCB   960      // comb-GEMM block slots (8 xcd * 20 * 6)

// Fixed level geometry (matches SPATIAL in the reference)
__constant__ int c_w[4]     = {176, 88, 44, 22};
__constant__ int c_h[4]     = {64, 32, 16, 8};
__constant__ int c_start[4] = {0, 11264, 14080, 14784};

using bf16x8 = __attribute__((ext_vector_type(8))) short;
using f32x4  = __attribute__((ext_vector_type(4))) float;

// direct-to-LDS 16B staging (dest = wave-uniform base + lane*16)
#define GLDS16(g, l)                                                         \
    __builtin_amdgcn_global_load_lds(                                        \
        (const __attribute__((address_space(1))) void*)(g),                  \
        (__attribute__((address_space(3))) void*)(l), 16, 0, 0)

// v_dot2_f32_f16: acc += p.h[0]*w.h[0] + p.h[1]*w.h[1]  (f32 accumulate)
static __device__ inline float fdot2_u(unsigned int p, unsigned int w, float c) {
    float r;
    asm("v_dot2_f32_f16 %0, %1, %2, %3" : "=v"(r) : "v"(p), "v"(w), "v"(c));
    return r;
}

// Truncation-based split: v ~= hi + lo with |dropped| <= 2^-16 |v|.
static __device__ inline void split_bf16(float v, unsigned short& hi, unsigned short& lo) {
    unsigned int u = __float_as_uint(v);
    hi = (unsigned short)(u >> 16);
    float hif = __uint_as_float(u & 0xFFFF0000u);
    float l = v - hif;
    lo = (unsigned short)(__float_as_uint(l) >> 16);
}

// round-to-nearest-even f32 -> bf16
static __device__ inline unsigned short f2bf_rne(float v) {
    unsigned int u = __float_as_uint(v);
    u += 0x7FFFu + ((u >> 16) & 1u);
    return (unsigned short)(u >> 16);
}

// round-to-nearest-even f32 -> f16 (bit pattern)
static __device__ inline unsigned short f2h_rne(float v) {
    _Float16 h = (_Float16)v;
    return __builtin_bit_cast(unsigned short, h);
}

// ---------------------------------------------------------------------------
// One-shot weight preprocessing: transpose to [N][K] (k-contiguous) and split
// into bf16 hi/lo pairs. Wo (256x512) and Wa (256x256) concatenated -> 768 cols.
// (~1 MB of traffic; ~4 us. The big input casts now happen inside gemm2's
// A staging — the separate 215 MB cast round-trip is gone.)
// ---------------------------------------------------------------------------
__global__ __launch_bounds__(256) void conv_weights(
    const float* __restrict__ Wv, const float* __restrict__ Wo,
    const float* __restrict__ Wa, const float* __restrict__ bo,
    const float* __restrict__ ba,
    unsigned short* __restrict__ Wv_hi, unsigned short* __restrict__ Wv_lo,
    unsigned short* __restrict__ Wc_hi, unsigned short* __restrict__ Wc_lo,
    float* __restrict__ bcomb)
{
    int id = blockIdx.x * 256 + threadIdx.x;
    if (id < 256 * 256) {                       // Wv -> Wv_t[n][k]
        int n = id >> 8, k = id & 255;
        unsigned short h, l;
        split_bf16(Wv[k * 256 + n], h, l);
        Wv_hi[id] = h; Wv_lo[id] = l;
    } else {                                    // [Wo | Wa] -> Wc_t[n][k]
        int id2 = id - 65536;
        if (id2 < 768 * 256) {
            int n = id2 >> 8, k = id2 & 255;
            float v = (n < 512) ? Wo[k * 512 + n] : Wa[k * 256 + (n - 512)];
            unsigned short h, l;
            split_bf16(v, h, l);
            Wc_hi[id2] = h; Wc_lo[id2] = l;
        }
    }
    if (id < 768) bcomb[id] = (id < 512) ? bo[id] : ba[id - 512];
}

// ---------------------------------------------------------------------------
// Stage-2: BOTH GEMMs in one dispatch by block-range concatenation (each
// block runs exactly its solo-kernel code path; no interleave).
//   bid <  NVB : value GEMM  input_flatten(f32) @ (Wvh+Wvl) -> f16 value
//   bid >= NVB : comb GEMM   query(f32)        @ (Wch+Wcl) -> f32 combq
// A path: f32 register-staged with in-register RNE f32->bf16 conversion
// (bit-identical to the old separate cast pass) + one ds_write_b128;
// 1-deep prefetch (tile kt+1 loads issued right after the barrier, a full
// MFMA phase of latency cover). B path: global_load_lds (unchanged).
// VGPR 56+8(prefetch) = 64 -> __launch_bounds__(512,8) holds 4 blocks/CU.
// ---------------------------------------------------------------------------
__global__ __launch_bounds__(512, 8) void gemm2(
    const float* __restrict__ Av,              // [MV_][256] f32 input_flatten
    const float* __restrict__ Aq,              // [MQ_][256] f32 query
    const unsigned short* __restrict__ Wvh, const unsigned short* __restrict__ Wvl,
    const unsigned short* __restrict__ Wch, const unsigned short* __restrict__ Wcl,
    const float* __restrict__ bv, const float* __restrict__ bc,
    float* __restrict__ Cq,                    // combq f32 (20000x768)
    unsigned short* __restrict__ Cv)           // value f16 (n,h,pix,dh)
{
    __shared__ __align__(16) unsigned short As [4096];  // [128][32]
    __shared__ __align__(16) unsigned short Bhs[4096];
    __shared__ __align__(16) unsigned short Bls[4096];

    const int tid = threadIdx.x;
    const int bid = blockIdx.x;
    const bool is_comb = (bid >= NVB);

    const float* A;
    const unsigned short *Bth, *Btl;
    const float* bias;
    int by, bx, M, N;
    if (is_comb) {
        // NVB % 8 == 0, so bid&7 == cid&7 (physical XCD residue preserved)
        int cid = bid - NVB;
        int xcd = cid & 7, j = cid >> 3;        // j in [0,120)
        by = xcd + 8 * (j / 6); bx = j % 6;
        if (by >= NBMQ) return;
        A = Aq; Bth = Wch; Btl = Wcl; bias = bc;
        M = MQ_; N = 768;
    } else {
        int xcd = bid & 7, j = bid >> 3;        // j in [0,234)
        by = xcd + 8 * (j >> 1); bx = j & 1;
        if (by >= NBMV) return;
        A = Av; Bth = Wvh; Btl = Wvl; bias = bv;
        M = MV_; N = 256;
    }

    const int row0 = by << 7, col0 = bx << 7;
    const int lane = tid & 63, wave = tid >> 6;
    const int wrow = (wave & 1) << 6, wcol = (wave >> 1) << 5;
    const int r16  = lane & 15, quad = lane >> 4;

    // staging: thread t -> row t>>2 (0..127), k-quarter t&3.
    const int srow = tid >> 2, skq = tid & 3;
    const int arow = min(row0 + srow, M - 1);   // clamp; epilogue masks
    const float* gA = A + (size_t)arow * KDIM + skq * 8;          // 32B/lane
    const unsigned short* gBh = Bth + (size_t)(col0 + srow) * KDIM + skq * 8;
    const unsigned short* gBl = Btl + (size_t)(col0 + srow) * KDIM + skq * 8;
    unsigned short* lBh = &Bhs[wave << 9];      // wave-uniform LDS bases
    unsigned short* lBl = &Bls[wave << 9];
    const int aoff = srow * 32 + skq * 8;       // A ds_write elem offset

    // prologue: A prefetch for tile 0
    float4 a0 = *(const float4*)(gA + 0);
    float4 a1 = *(const float4*)(gA + 4);

    f32x4 acc[4][2];
#pragma unroll
    for (int i = 0; i < 4; ++i)
#pragma unroll
        for (int j = 0; j < 2; ++j) acc[i][j] = (f32x4){0.f, 0.f, 0.f, 0.f};

#pragma unroll
    for (int kt = 0; kt < 8; ++kt) {
        // ---- B: direct to LDS (async) ----
        GLDS16(gBh + kt * 32, lBh);
        GLDS16(gBl + kt * 32, lBl);
        // ---- A: in-register RNE cvt + one b128 LDS write ----
        {
            bf16x8 hv;
            hv[0] = (short)f2bf_rne(a0.x); hv[1] = (short)f2bf_rne(a0.y);
            hv[2] = (short)f2bf_rne(a0.z); hv[3] = (short)f2bf_rne(a0.w);
            hv[4] = (short)f2bf_rne(a1.x); hv[5] = (short)f2bf_rne(a1.y);
            hv[6] = (short)f2bf_rne(a1.z); hv[7] = (short)f2bf_rne(a1.w);
            *(bf16x8*)&As[aoff] = hv;
        }
        __syncthreads();                        // drains glds + ds_write

        // ---- A prefetch for tile kt+1 (covered by fragments + MFMA) ----
        if (kt < 7) {
            a0 = *(const float4*)(gA + (kt + 1) * 32);
            a1 = *(const float4*)(gA + (kt + 1) * 32 + 4);
        }

        // ---- fragments + MFMA ----
        bf16x8 fbh[2], fbl[2], fa[4];
#pragma unroll
        for (int tn = 0; tn < 2; ++tn) {
            int n = wcol + tn * 16 + r16;
            fbh[tn] = *(const bf16x8*)&Bhs[n * 32 + (quad << 3)];
            fbl[tn] = *(const bf16x8*)&Bls[n * 32 + (quad << 3)];
        }
#pragma unroll
        for (int tm = 0; tm < 4; ++tm)
            fa[tm] = *(const bf16x8*)&As[(wrow + tm * 16 + r16) * 32 + (quad << 3)];
#pragma unroll
        for (int tm = 0; tm < 4; ++tm)
#pragma unroll
            for (int tn = 0; tn < 2; ++tn) {
                acc[tm][tn] = __builtin_amdgcn_mfma_f32_16x16x32_bf16(fa[tm], fbl[tn], acc[tm][tn], 0, 0, 0);
                acc[tm][tn] = __builtin_amdgcn_mfma_f32_16x16x32_bf16(fa[tm], fbh[tn], acc[tm][tn], 0, 0, 0);
            }
        __syncthreads();
    }

    // ---- epilogue: C/D layout col=lane&15, row=quad*4+reg ----
    float bvs[2];
#pragma unroll
    for (int tn = 0; tn < 2; ++tn) bvs[tn] = bias[col0 + wcol + tn * 16 + r16];
#pragma unroll
    for (int tm = 0; tm < 4; ++tm) {
#pragma unroll
        for (int i = 0; i < 4; ++i) {
            int row = row0 + wrow + tm * 16 + (quad << 2) + i;
            if (row < M) {
                if (is_comb) {
                    float* crow = Cq + (size_t)row * N + col0 + wcol + r16;
#pragma unroll
                    for (int tn = 0; tn < 2; ++tn)
                        crow[tn * 16] = acc[tm][tn][i] + bvs[tn];
                } else {
                    int n   = row / LEN_IN_;
                    int pix = row - n * LEN_IN_;
#pragma unroll
                    for (int tn = 0; tn < 2; ++tn) {
                        int col = col0 + wcol + tn * 16 + r16;
                        int h = col >> 5, dh = col & 31;
                        size_t addr = ((size_t)(n * NH_ + h) * LEN_IN_ + pix) * DH_ + dh;
                        Cv[addr] = f2h_rne(acc[tm][tn][i] + bvs[tn]);
                    }
                }
            }
        }
    }
}

// ---------------------------------------------------------------------------
// Fused softmax + loc + bilinear sampling, XCD-locality version.
// Block = one (n, head) value slice (957 KB) x 64 queries; blockIdx swizzled
// so all blocks of a slice run on one XCD -> slice lives in that XCD's L2.
//   grid = 2560: xcd = b&7, j = b>>3, slice = (j/40)*8 + xcd, chunk = j%40.
// Stage: 256 thr = (q_local, l) -> 16B descriptors (ushort4 idx + half4 w).
// Gather: 256 thr = (q_local, dhg); value is f16 so two corners fold into one
// v_dot2_f32_f16 per channel pair (v_perm_b32 packs per-channel corner pairs;
// weights consumed directly as the packed half2 descriptor words).
// ---------------------------------------------------------------------------
__global__ __launch_bounds__(256, 4) void ms_sample(
    const unsigned short* __restrict__ value,  // (n, 8, len_in, 32) f16
    const float* __restrict__ comb,            // (n*lq, 768): off(512) | logit(256)
    const float* __restrict__ ref_pts,         // (n*lq, 4, 2)
    float* __restrict__ out)                   // (n*lq, 256)
{
    __shared__ uint4 s_desc[64][33];

    const int b     = blockIdx.x;
    const int xcd   = b & 7;
    const int j     = b >> 3;
    const int slice = (j / 40) * 8 + xcd;      // 0..63
    const int chunk = j % 40;
    const int n     = slice >> 3, h = slice & 7;
    const int q0    = chunk * 64;
    const int tid   = threadIdx.x;

    { // ---- stage ----
        int ql = tid >> 2, l = tid & 3;
        int q  = q0 + ql;
        if (q < LQ_) {
            int nq = n * LQ_ + q;
            const float* row = comb + (size_t)nq * 768;

            float4 L0 = *(const float4*)&row[512 + h * 32 + l * 8];
            float4 L1 = *(const float4*)&row[512 + h * 32 + l * 8 + 4];
            float lg[8] = {L0.x, L0.y, L0.z, L0.w, L1.x, L1.y, L1.z, L1.w};
            float m = lg[0];
#pragma unroll
            for (int i = 1; i < 8; ++i) m = fmaxf(m, lg[i]);
            m = fmaxf(m, __shfl_xor(m, 1));
            m = fmaxf(m, __shfl_xor(m, 2));
            float e[8], s = 0.f;
#pragma unroll
            for (int i = 0; i < 8; ++i) { e[i] = __expf(lg[i] - m); s += e[i]; }
            s += __shfl_xor(s, 1);
            s += __shfl_xor(s, 2);
            float inv = 1.f / s;

            float4 R0 = *(const float4*)&ref_pts[(size_t)nq * 8];
            float4 R1 = *(const float4*)&ref_pts[(size_t)nq * 8 + 4];
            float rx[4] = {R0.x, R0.z, R1.x, R1.z};
            float ry[4] = {R0.y, R0.w, R1.y, R1.w};

            float off[16];
#pragma unroll
            for (int i = 0; i < 4; ++i)
                *(float4*)&off[i * 4] = *(const float4*)&row[h * 64 + l * 16 + i * 4];

            float wl = (float)c_w[l], hl = (float)c_h[l];
            int wli = c_w[l], hli = c_h[l], st = c_start[l];
#pragma unroll
            for (int p = 0; p < 8; ++p) {
                int z = p & 3;
                float a = e[p] * inv;
                float x = rx[z] * wl + off[p * 2 + 0] - 0.5f;
                float y = ry[z] * hl + off[p * 2 + 1] - 0.5f;
                float x0f = floorf(x), y0f = floorf(y);
                int   x0 = (int)x0f,  y0 = (int)y0f;
                float wx = x - x0f,   wy = y - y0f;
                unsigned short ix[4];
                float wt[4];
#pragma unroll
                for (int jj = 0; jj < 4; ++jj) {
                    int xi = x0 + (jj & 1);
                    int yi = y0 + (jj >> 1);
                    float w = ((jj & 1) ? wx : 1.f - wx) * ((jj >> 1) ? wy : 1.f - wy);
                    bool valid = (xi >= 0) && (xi < wli) && (yi >= 0) && (yi < hli);
                    int xc = min(max(xi, 0), wli - 1);
                    int yc = min(max(yi, 0), hli - 1);
                    ix[jj] = (unsigned short)(yc * wli + xc);
                    wt[jj] = valid ? a * w : 0.f;
                }
                uint4 d;
                d.x = (unsigned int)(st + ix[0]) | ((unsigned int)(st + ix[1]) << 16);
                d.y = (unsigned int)(st + ix[2]) | ((unsigned int)(st + ix[3]) << 16);
                __half2 h01 = __floats2half2_rn(wt[0], wt[1]);
                __half2 h23 = __floats2half2_rn(wt[2], wt[3]);
                d.z = *(unsigned int*)&h01;
                d.w = *(unsigned int*)&h23;
                s_desc[ql][l * 8 + p] = d;
            }
        }
    }
    __syncthreads();

    // ---- gather (value accesses confined to this block's (n,h) slice) ----
    int ql = tid >> 2, dhg = tid & 3;
    int q  = q0 + ql;
    if (q >= LQ_) return;
    int nq = n * LQ_ + q;
    const unsigned short* vb = value
        + ((size_t)(n * NH_ + h) * LEN_IN_) * DH_ + dhg * 8;

    float acc[8];
#pragma unroll
    for (int i = 0; i < 8; ++i) acc[i] = 0.f;

#pragma unroll 4
    for (int s = 0; s < 32; ++s) {
        uint4 d = s_desc[ql][s];
        int i0 = d.x & 0xFFFF, i1 = d.x >> 16;
        int i2 = d.y & 0xFFFF, i3 = d.y >> 16;
        uint4 v0 = *(const uint4*)(vb + i0 * DH_);
        uint4 v1 = *(const uint4*)(vb + i1 * DH_);
        uint4 v2 = *(const uint4*)(vb + i2 * DH_);
        uint4 v3 = *(const uint4*)(vb + i3 * DH_);
        // corners 0,1 -> weights d.z ; corners 2,3 -> weights d.w
        acc[0] = fdot2_u(__builtin_amdgcn_perm(v1.x, v0.x, 0x05040100u), d.z, acc[0]);
        acc[1] = fdot2_u(__builtin_amdgcn_perm(v1.x, v0.x, 0x07060302u), d.z, acc[1]);
        acc[2] = fdot2_u(__builtin_amdgcn_perm(v1.y, v0.y, 0x05040100u), d.z, acc[2]);
        acc[3] = fdot2_u(__builtin_amdgcn_perm(v1.y, v0.y, 0x07060302u), d.z, acc[3]);
        acc[4] = fdot2_u(__builtin_amdgcn_perm(v1.z, v0.z, 0x05040100u), d.z, acc[4]);
        acc[5] = fdot2_u(__builtin_amdgcn_perm(v1.z, v0.z, 0x07060302u), d.z, acc[5]);
        acc[6] = fdot2_u(__builtin_amdgcn_perm(v1.w, v0.w, 0x05040100u), d.z, acc[6]);
        acc[7] = fdot2_u(__builtin_amdgcn_perm(v1.w, v0.w, 0x07060302u), d.z, acc[7]);
        acc[0] = fdot2_u(__builtin_amdgcn_perm(v3.x, v2.x, 0x05040100u), d.w, acc[0]);
        acc[1] = fdot2_u(__builtin_amdgcn_perm(v3.x, v2.x, 0x07060302u), d.w, acc[1]);
        acc[2] = fdot2_u(__builtin_amdgcn_perm(v3.y, v2.y, 0x05040100u), d.w, acc[2]);
        acc[3] = fdot2_u(__builtin_amdgcn_perm(v3.y, v2.y, 0x07060302u), d.w, acc[3]);
        acc[4] = fdot2_u(__builtin_amdgcn_perm(v3.z, v2.z, 0x05040100u), d.w, acc[4]);
        acc[5] = fdot2_u(__builtin_amdgcn_perm(v3.z, v2.z, 0x07060302u), d.w, acc[5]);
        acc[6] = fdot2_u(__builtin_amdgcn_perm(v3.w, v2.w, 0x05040100u), d.w, acc[6]);
        acc[7] = fdot2_u(__builtin_amdgcn_perm(v3.w, v2.w, 0x07060302u), d.w, acc[7]);
    }

    float* op = out + (size_t)nq * 256 + h * 32 + dhg * 8;
    *(float4*)&op[0] = make_float4(acc[0], acc[1], acc[2], acc[3]);
    *(float4*)&op[4] = make_float4(acc[4], acc[5], acc[6], acc[7]);
}

// ---------------------------------------------------------------------------
extern "C" void kernel_launch(void* const* d_in, const int* in_sizes, int n_in,
                              void* d_out, int out_size, void* d_ws, size_t ws_size,
                              hipStream_t stream)
{
    const float* query         = (const float*)d_in[0];
    const float* ref_pts       = (const float*)d_in[2];
    const float* input_flatten = (const float*)d_in[3];
    const float* Wv            = (const float*)d_in[6];
    const float* bv            = (const float*)d_in[7];
    const float* Wo            = (const float*)d_in[8];
    const float* bo            = (const float*)d_in[9];
    const float* Wa            = (const float*)d_in[10];
    const float* ba            = (const float*)d_in[11];
    float* out = (float*)d_out;

    char* ws = (char*)d_ws;
    size_t o = 0;
    unsigned short* Wv_hi = (unsigned short*)(ws + o); o += 256 * 256 * 2;
    unsigned short* Wv_lo = (unsigned short*)(ws + o); o += 256 * 256 * 2;
    unsigned short* Wc_hi = (unsigned short*)(ws + o); o += 768 * 256 * 2;
    unsigned short* Wc_lo = (unsigned short*)(ws + o); o += 768 * 256 * 2;
    float*          bcomb = (float*)(ws + o);          o += 768 * 4;
    o = (o + 511) & ~(size_t)511;
    unsigned short* value = (unsigned short*)(ws + o); o += (size_t)119680 * 256 * 2;
    o = (o + 511) & ~(size_t)511;
    float* combq = (float*)(ws + o); o += (size_t)20000 * 768 * 4;

    // stage 1: weights only (~1 MB)
    hipLaunchKernelGGL(conv_weights, dim3(1024), dim3(256), 0, stream,
                       Wv, Wo, Wa, bo, ba, Wv_hi, Wv_lo, Wc_hi, Wc_lo, bcomb);
    // stage 2: both GEMMs, one dispatch; A cast folded into staging
    hipLaunchKernelGGL(gemm2, dim3(NVB + NCB), dim3(512), 0, stream,
                       input_flatten, query, Wv_hi, Wv_lo, Wc_hi, Wc_lo,
                       bv, bcomb, combq, value);
    // stage 3: fused softmax + loc + bilinear sample + weighted sum
    hipLaunchKernelGGL(ms_sample, dim3(2560), dim3(256), 0, stream,
                       value, combq, ref_pts, out);
}

// Round 6
// 345.538 us; speedup vs baseline: 1.4699x; 1.4699x over previous
//
#include <hip/hip_runtime.h>
#include <hip/hip_fp16.h>

#define N_BATCH 8
#define LQ_     2500
#define DM_     256
#define NH_     8
#define NL_     4
#define NP_     8
#define DH_     32
#define LEN_IN_ 14960
#define KDIM    256

#define MV_   119680   // N_BATCH * LEN_IN_
#define MQ_   20000    // N_BATCH * LQ_
#define NBMV  935      // MV_/128 row panels (exact)
#define NBMQ  157      // ceil(MQ_/128) row panels
#define NVB   1872     // value-GEMM block slots (8 xcd * 117 * 2, 2 idle)
#define NCB   960      // comb-GEMM block slots (8 xcd * 20 * 6)

// Fixed level geometry (matches SPATIAL in the reference)
__constant__ int c_w[4]     = {176, 88, 44, 22};
__constant__ int c_h[4]     = {64, 32, 16, 8};
__constant__ int c_start[4] = {0, 11264, 14080, 14784};

using bf16x8 = __attribute__((ext_vector_type(8))) short;
using f32x4  = __attribute__((ext_vector_type(4))) float;

// direct-to-LDS 16B staging (dest = wave-uniform base + lane*16)
#define GLDS16(g, l)                                                         \
    __builtin_amdgcn_global_load_lds(                                        \
        (const __attribute__((address_space(1))) void*)(g),                  \
        (__attribute__((address_space(3))) void*)(l), 16, 0, 0)

// v_dot2_f32_f16: acc += p.h[0]*w.h[0] + p.h[1]*w.h[1]  (f32 accumulate)
static __device__ inline float fdot2_u(unsigned int p, unsigned int w, float c) {
    float r;
    asm("v_dot2_f32_f16 %0, %1, %2, %3" : "=v"(r) : "v"(p), "v"(w), "v"(c));
    return r;
}

// Truncation-based split: v ~= hi + lo with |dropped| <= 2^-16 |v|.
static __device__ inline void split_bf16(float v, unsigned short& hi, unsigned short& lo) {
    unsigned int u = __float_as_uint(v);
    hi = (unsigned short)(u >> 16);
    float hif = __uint_as_float(u & 0xFFFF0000u);
    float l = v - hif;
    lo = (unsigned short)(__float_as_uint(l) >> 16);
}

// round-to-nearest-even f32 -> bf16
static __device__ inline unsigned short f2bf_rne(float v) {
    unsigned int u = __float_as_uint(v);
    u += 0x7FFFu + ((u >> 16) & 1u);
    return (unsigned short)(u >> 16);
}

// round-to-nearest-even f32 -> f16 (bit pattern)
static __device__ inline unsigned short f2h_rne(float v) {
    _Float16 h = (_Float16)v;
    return __builtin_bit_cast(unsigned short, h);
}

// ---------------------------------------------------------------------------
// One-shot weight preprocessing: transpose to [N][K] (k-contiguous) and split
// into bf16 hi/lo pairs. Wo (256x512) and Wa (256x256) concatenated -> 768 cols.
// (~1 MB of traffic; the big input casts happen inside gemm2's A staging.)
// ---------------------------------------------------------------------------
__global__ __launch_bounds__(256) void conv_weights(
    const float* __restrict__ Wv, const float* __restrict__ Wo,
    const float* __restrict__ Wa, const float* __restrict__ bo,
    const float* __restrict__ ba,
    unsigned short* __restrict__ Wv_hi, unsigned short* __restrict__ Wv_lo,
    unsigned short* __restrict__ Wc_hi, unsigned short* __restrict__ Wc_lo,
    float* __restrict__ bcomb)
{
    int id = blockIdx.x * 256 + threadIdx.x;
    if (id < 256 * 256) {                       // Wv -> Wv_t[n][k]
        int n = id >> 8, k = id & 255;
        unsigned short h, l;
        split_bf16(Wv[k * 256 + n], h, l);
        Wv_hi[id] = h; Wv_lo[id] = l;
    } else {                                    // [Wo | Wa] -> Wc_t[n][k]
        int id2 = id - 65536;
        if (id2 < 768 * 256) {
            int n = id2 >> 8, k = id2 & 255;
            float v = (n < 512) ? Wo[k * 512 + n] : Wa[k * 256 + (n - 512)];
            unsigned short h, l;
            split_bf16(v, h, l);
            Wc_hi[id2] = h; Wc_lo[id2] = l;
        }
    }
    if (id < 768) bcomb[id] = (id < 512) ? bo[id] : ba[id - 512];
}

// ---------------------------------------------------------------------------
// Stage-2: BOTH GEMMs in one dispatch by block-range concatenation.
//   bid <  NVB : value GEMM  input_flatten(f32) @ (Wvh+Wvl) -> f16 value
//   bid >= NVB : comb GEMM   query(f32)        @ (Wch+Wcl) -> f32 combq
// A path: f32 register-staged with in-register RNE f32->bf16 conversion
// + one ds_write_b128; 1-deep prefetch. B path: global_load_lds.
// __launch_bounds__(512, 4): 128-reg budget — acc takes 32 AGPRs (unified
// file!) + ~70-95 VGPRs, NO SPILL. Round 5's (512,8) forced a 64-reg budget
// -> 434 MB of scratch writes (WRITE_SIZE 557 MB) and a 3x slowdown.
// ---------------------------------------------------------------------------
__global__ __launch_bounds__(512, 4) void gemm2(
    const float* __restrict__ Av,              // [MV_][256] f32 input_flatten
    const float* __restrict__ Aq,              // [MQ_][256] f32 query
    const unsigned short* __restrict__ Wvh, const unsigned short* __restrict__ Wvl,
    const unsigned short* __restrict__ Wch, const unsigned short* __restrict__ Wcl,
    const float* __restrict__ bv, const float* __restrict__ bc,
    float* __restrict__ Cq,                    // combq f32 (20000x768)
    unsigned short* __restrict__ Cv)           // value f16 (n,h,pix,dh)
{
    __shared__ __align__(16) unsigned short As [4096];  // [128][32]
    __shared__ __align__(16) unsigned short Bhs[4096];
    __shared__ __align__(16) unsigned short Bls[4096];

    const int tid = threadIdx.x;
    const int bid = blockIdx.x;
    const bool is_comb = (bid >= NVB);

    const float* A;
    const unsigned short *Bth, *Btl;
    const float* bias;
    int by, bx, M, N;
    if (is_comb) {
        // NVB % 8 == 0, so bid&7 == cid&7 (physical XCD residue preserved)
        int cid = bid - NVB;
        int xcd = cid & 7, j = cid >> 3;        // j in [0,120)
        by = xcd + 8 * (j / 6); bx = j % 6;
        if (by >= NBMQ) return;
        A = Aq; Bth = Wch; Btl = Wcl; bias = bc;
        M = MQ_; N = 768;
    } else {
        int xcd = bid & 7, j = bid >> 3;        // j in [0,234)
        by = xcd + 8 * (j >> 1); bx = j & 1;
        if (by >= NBMV) return;
        A = Av; Bth = Wvh; Btl = Wvl; bias = bv;
        M = MV_; N = 256;
    }

    const int row0 = by << 7, col0 = bx << 7;
    const int lane = tid & 63, wave = tid >> 6;
    const int wrow = (wave & 1) << 6, wcol = (wave >> 1) << 5;
    const int r16  = lane & 15, quad = lane >> 4;

    // staging: thread t -> row t>>2 (0..127), k-quarter t&3.
    const int srow = tid >> 2, skq = tid & 3;
    const int arow = min(row0 + srow, M - 1);   // clamp; epilogue masks
    const float* gA = A + (size_t)arow * KDIM + skq * 8;          // 32B/lane
    const unsigned short* gBh = Bth + (size_t)(col0 + srow) * KDIM + skq * 8;
    const unsigned short* gBl = Btl + (size_t)(col0 + srow) * KDIM + skq * 8;
    unsigned short* lBh = &Bhs[wave << 9];      // wave-uniform LDS bases
    unsigned short* lBl = &Bls[wave << 9];
    const int aoff = srow * 32 + skq * 8;       // A ds_write elem offset

    // prologue: A prefetch for tile 0
    float4 a0 = *(const float4*)(gA + 0);
    float4 a1 = *(const float4*)(gA + 4);

    f32x4 acc[4][2];
#pragma unroll
    for (int i = 0; i < 4; ++i)
#pragma unroll
        for (int j = 0; j < 2; ++j) acc[i][j] = (f32x4){0.f, 0.f, 0.f, 0.f};

#pragma unroll
    for (int kt = 0; kt < 8; ++kt) {
        // ---- B: direct to LDS (async) ----
        GLDS16(gBh + kt * 32, lBh);
        GLDS16(gBl + kt * 32, lBl);
        // ---- A: in-register RNE cvt + one b128 LDS write ----
        {
            bf16x8 hv;
            hv[0] = (short)f2bf_rne(a0.x); hv[1] = (short)f2bf_rne(a0.y);
            hv[2] = (short)f2bf_rne(a0.z); hv[3] = (short)f2bf_rne(a0.w);
            hv[4] = (short)f2bf_rne(a1.x); hv[5] = (short)f2bf_rne(a1.y);
            hv[6] = (short)f2bf_rne(a1.z); hv[7] = (short)f2bf_rne(a1.w);
            *(bf16x8*)&As[aoff] = hv;
        }
        __syncthreads();                        // drains glds + ds_write

        // ---- A prefetch for tile kt+1 (covered by fragments + MFMA) ----
        if (kt < 7) {
            a0 = *(const float4*)(gA + (kt + 1) * 32);
            a1 = *(const float4*)(gA + (kt + 1) * 32 + 4);
        }

        // ---- fragments + MFMA ----
        bf16x8 fbh[2], fbl[2], fa[4];
#pragma unroll
        for (int tn = 0; tn < 2; ++tn) {
            int n = wcol + tn * 16 + r16;
            fbh[tn] = *(const bf16x8*)&Bhs[n * 32 + (quad << 3)];
            fbl[tn] = *(const bf16x8*)&Bls[n * 32 + (quad << 3)];
        }
#pragma unroll
        for (int tm = 0; tm < 4; ++tm)
            fa[tm] = *(const bf16x8*)&As[(wrow + tm * 16 + r16) * 32 + (quad << 3)];
#pragma unroll
        for (int tm = 0; tm < 4; ++tm)
#pragma unroll
            for (int tn = 0; tn < 2; ++tn) {
                acc[tm][tn] = __builtin_amdgcn_mfma_f32_16x16x32_bf16(fa[tm], fbl[tn], acc[tm][tn], 0, 0, 0);
                acc[tm][tn] = __builtin_amdgcn_mfma_f32_16x16x32_bf16(fa[tm], fbh[tn], acc[tm][tn], 0, 0, 0);
            }
        __syncthreads();
    }

    // ---- epilogue: C/D layout col=lane&15, row=quad*4+reg ----
    float bvs[2];
#pragma unroll
    for (int tn = 0; tn < 2; ++tn) bvs[tn] = bias[col0 + wcol + tn * 16 + r16];
#pragma unroll
    for (int tm = 0; tm < 4; ++tm) {
#pragma unroll
        for (int i = 0; i < 4; ++i) {
            int row = row0 + wrow + tm * 16 + (quad << 2) + i;
            if (row < M) {
                if (is_comb) {
                    float* crow = Cq + (size_t)row * N + col0 + wcol + r16;
#pragma unroll
                    for (int tn = 0; tn < 2; ++tn)
                        crow[tn * 16] = acc[tm][tn][i] + bvs[tn];
                } else {
                    int n   = row / LEN_IN_;
                    int pix = row - n * LEN_IN_;
#pragma unroll
                    for (int tn = 0; tn < 2; ++tn) {
                        int col = col0 + wcol + tn * 16 + r16;
                        int h = col >> 5, dh = col & 31;
                        size_t addr = ((size_t)(n * NH_ + h) * LEN_IN_ + pix) * DH_ + dh;
                        Cv[addr] = f2h_rne(acc[tm][tn][i] + bvs[tn]);
                    }
                }
            }
        }
    }
}

// ---------------------------------------------------------------------------
// Fused softmax + loc + bilinear sampling, XCD-locality version.
// Block = one (n, head) value slice (957 KB) x 64 queries; blockIdx swizzled
// so all blocks of a slice run on one XCD -> slice lives in that XCD's L2.
//   grid = 2560: xcd = b&7, j = b>>3, slice = (j/40)*8 + xcd, chunk = j%40.
// Stage: 256 thr = (q_local, l) -> 16B descriptors (ushort4 idx + half4 w).
// Gather: 256 thr = (q_local, dhg); value is f16 so two corners fold into one
// v_dot2_f32_f16 per channel pair (v_perm_b32 packs per-channel corner pairs;
// weights consumed directly as the packed half2 descriptor words).
// ---------------------------------------------------------------------------
__global__ __launch_bounds__(256, 4) void ms_sample(
    const unsigned short* __restrict__ value,  // (n, 8, len_in, 32) f16
    const float* __restrict__ comb,            // (n*lq, 768): off(512) | logit(256)
    const float* __restrict__ ref_pts,         // (n*lq, 4, 2)
    float* __restrict__ out)                   // (n*lq, 256)
{
    __shared__ uint4 s_desc[64][33];

    const int b     = blockIdx.x;
    const int xcd   = b & 7;
    const int j     = b >> 3;
    const int slice = (j / 40) * 8 + xcd;      // 0..63
    const int chunk = j % 40;
    const int n     = slice >> 3, h = slice & 7;
    const int q0    = chunk * 64;
    const int tid   = threadIdx.x;

    { // ---- stage ----
        int ql = tid >> 2, l = tid & 3;
        int q  = q0 + ql;
        if (q < LQ_) {
            int nq = n * LQ_ + q;
            const float* row = comb + (size_t)nq * 768;

            float4 L0 = *(const float4*)&row[512 + h * 32 + l * 8];
            float4 L1 = *(const float4*)&row[512 + h * 32 + l * 8 + 4];
            float lg[8] = {L0.x, L0.y, L0.z, L0.w, L1.x, L1.y, L1.z, L1.w};
            float m = lg[0];
#pragma unroll
            for (int i = 1; i < 8; ++i) m = fmaxf(m, lg[i]);
            m = fmaxf(m, __shfl_xor(m, 1));
            m = fmaxf(m, __shfl_xor(m, 2));
            float e[8], s = 0.f;
#pragma unroll
            for (int i = 0; i < 8; ++i) { e[i] = __expf(lg[i] - m); s += e[i]; }
            s += __shfl_xor(s, 1);
            s += __shfl_xor(s, 2);
            float inv = 1.f / s;

            float4 R0 = *(const float4*)&ref_pts[(size_t)nq * 8];
            float4 R1 = *(const float4*)&ref_pts[(size_t)nq * 8 + 4];
            float rx[4] = {R0.x, R0.z, R1.x, R1.z};
            float ry[4] = {R0.y, R0.w, R1.y, R1.w};

            float off[16];
#pragma unroll
            for (int i = 0; i < 4; ++i)
                *(float4*)&off[i * 4] = *(const float4*)&row[h * 64 + l * 16 + i * 4];

            float wl = (float)c_w[l], hl = (float)c_h[l];
            int wli = c_w[l], hli = c_h[l], st = c_start[l];
#pragma unroll
            for (int p = 0; p < 8; ++p) {
                int z = p & 3;
                float a = e[p] * inv;
                float x = rx[z] * wl + off[p * 2 + 0] - 0.5f;
                float y = ry[z] * hl + off[p * 2 + 1] - 0.5f;
                float x0f = floorf(x), y0f = floorf(y);
                int   x0 = (int)x0f,  y0 = (int)y0f;
                float wx = x - x0f,   wy = y - y0f;
                unsigned short ix[4];
                float wt[4];
#pragma unroll
                for (int jj = 0; jj < 4; ++jj) {
                    int xi = x0 + (jj & 1);
                    int yi = y0 + (jj >> 1);
                    float w = ((jj & 1) ? wx : 1.f - wx) * ((jj >> 1) ? wy : 1.f - wy);
                    bool valid = (xi >= 0) && (xi < wli) && (yi >= 0) && (yi < hli);
                    int xc = min(max(xi, 0), wli - 1);
                    int yc = min(max(yi, 0), hli - 1);
                    ix[jj] = (unsigned short)(yc * wli + xc);
                    wt[jj] = valid ? a * w : 0.f;
                }
                uint4 d;
                d.x = (unsigned int)(st + ix[0]) | ((unsigned int)(st + ix[1]) << 16);
                d.y = (unsigned int)(st + ix[2]) | ((unsigned int)(st + ix[3]) << 16);
                __half2 h01 = __floats2half2_rn(wt[0], wt[1]);
                __half2 h23 = __floats2half2_rn(wt[2], wt[3]);
                d.z = *(unsigned int*)&h01;
                d.w = *(unsigned int*)&h23;
                s_desc[ql][l * 8 + p] = d;
            }
        }
    }
    __syncthreads();

    // ---- gather (value accesses confined to this block's (n,h) slice) ----
    int ql = tid >> 2, dhg = tid & 3;
    int q  = q0 + ql;
    if (q >= LQ_) return;
    int nq = n * LQ_ + q;
    const unsigned short* vb = value
        + ((size_t)(n * NH_ + h) * LEN_IN_) * DH_ + dhg * 8;

    float acc[8];
#pragma unroll
    for (int i = 0; i < 8; ++i) acc[i] = 0.f;

#pragma unroll 4
    for (int s = 0; s < 32; ++s) {
        uint4 d = s_desc[ql][s];
        int i0 = d.x & 0xFFFF, i1 = d.x >> 16;
        int i2 = d.y & 0xFFFF, i3 = d.y >> 16;
        uint4 v0 = *(const uint4*)(vb + i0 * DH_);
        uint4 v1 = *(const uint4*)(vb + i1 * DH_);
        uint4 v2 = *(const uint4*)(vb + i2 * DH_);
        uint4 v3 = *(const uint4*)(vb + i3 * DH_);
        // corners 0,1 -> weights d.z ; corners 2,3 -> weights d.w
        acc[0] = fdot2_u(__builtin_amdgcn_perm(v1.x, v0.x, 0x05040100u), d.z, acc[0]);
        acc[1] = fdot2_u(__builtin_amdgcn_perm(v1.x, v0.x, 0x07060302u), d.z, acc[1]);
        acc[2] = fdot2_u(__builtin_amdgcn_perm(v1.y, v0.y, 0x05040100u), d.z, acc[2]);
        acc[3] = fdot2_u(__builtin_amdgcn_perm(v1.y, v0.y, 0x07060302u), d.z, acc[3]);
        acc[4] = fdot2_u(__builtin_amdgcn_perm(v1.z, v0.z, 0x05040100u), d.z, acc[4]);
        acc[5] = fdot2_u(__builtin_amdgcn_perm(v1.z, v0.z, 0x07060302u), d.z, acc[5]);
        acc[6] = fdot2_u(__builtin_amdgcn_perm(v1.w, v0.w, 0x05040100u), d.z, acc[6]);
        acc[7] = fdot2_u(__builtin_amdgcn_perm(v1.w, v0.w, 0x07060302u), d.z, acc[7]);
        acc[0] = fdot2_u(__builtin_amdgcn_perm(v3.x, v2.x, 0x05040100u), d.w, acc[0]);
        acc[1] = fdot2_u(__builtin_amdgcn_perm(v3.x, v2.x, 0x07060302u), d.w, acc[1]);
        acc[2] = fdot2_u(__builtin_amdgcn_perm(v3.y, v2.y, 0x05040100u), d.w, acc[2]);
        acc[3] = fdot2_u(__builtin_amdgcn_perm(v3.y, v2.y, 0x07060302u), d.w, acc[3]);
        acc[4] = fdot2_u(__builtin_amdgcn_perm(v3.z, v2.z, 0x05040100u), d.w, acc[4]);
        acc[5] = fdot2_u(__builtin_amdgcn_perm(v3.z, v2.z, 0x07060302u), d.w, acc[5]);
        acc[6] = fdot2_u(__builtin_amdgcn_perm(v3.w, v2.w, 0x05040100u), d.w, acc[6]);
        acc[7] = fdot2_u(__builtin_amdgcn_perm(v3.w, v2.w, 0x07060302u), d.w, acc[7]);
    }

    float* op = out + (size_t)nq * 256 + h * 32 + dhg * 8;
    *(float4*)&op[0] = make_float4(acc[0], acc[1], acc[2], acc[3]);
    *(float4*)&op[4] = make_float4(acc[4], acc[5], acc[6], acc[7]);
}

// ---------------------------------------------------------------------------
extern "C" void kernel_launch(void* const* d_in, const int* in_sizes, int n_in,
                              void* d_out, int out_size, void* d_ws, size_t ws_size,
                              hipStream_t stream)
{
    const float* query         = (const float*)d_in[0];
    const float* ref_pts       = (const float*)d_in[2];
    const float* input_flatten = (const float*)d_in[3];
    const float* Wv            = (const float*)d_in[6];
    const float* bv            = (const float*)d_in[7];
    const float* Wo            = (const float*)d_in[8];
    const float* bo            = (const float*)d_in[9];
    const float* Wa            = (const float*)d_in[10];
    const float* ba            = (const float*)d_in[11];
    float* out = (float*)d_out;

    char* ws = (char*)d_ws;
    size_t o = 0;
    unsigned short* Wv_hi = (unsigned short*)(ws + o); o += 256 * 256 * 2;
    unsigned short* Wv_lo = (unsigned short*)(ws + o); o += 256 * 256 * 2;
    unsigned short* Wc_hi = (unsigned short*)(ws + o); o += 768 * 256 * 2;
    unsigned short* Wc_lo = (unsigned short*)(ws + o); o += 768 * 256 * 2;
    float*          bcomb = (float*)(ws + o);          o += 768 * 4;
    o = (o + 511) & ~(size_t)511;
    unsigned short* value = (unsigned short*)(ws + o); o += (size_t)119680 * 256 * 2;
    o = (o + 511) & ~(size_t)511;
    float* combq = (float*)(ws + o); o += (size_t)20000 * 768 * 4;

    // stage 1: weights only (~1 MB)
    hipLaunchKernelGGL(conv_weights, dim3(1024), dim3(256), 0, stream,
                       Wv, Wo, Wa, bo, ba, Wv_hi, Wv_lo, Wc_hi, Wc_lo, bcomb);
    // stage 2: both GEMMs, one dispatch; A cast folded into staging
    hipLaunchKernelGGL(gemm2, dim3(NVB + NCB), dim3(512), 0, stream,
                       input_flatten, query, Wv_hi, Wv_lo, Wc_hi, Wc_lo,
                       bv, bcomb, combq, value);
    // stage 3: fused softmax + loc + bilinear sample + weighted sum
    hipLaunchKernelGGL(ms_sample, dim3(2560), dim3(256), 0, stream,
                       value, combq, ref_pts, out);
}

// Round 7
// 340.891 us; speedup vs baseline: 1.4899x; 1.0136x over previous
//
#include <hip/hip_runtime.h>
#include <hip/hip_fp16.h>

#define N_BATCH 8
#define LQ_     2500
#define DM_     256
#define NH_     8
#define NL_     4
#define NP_     8
#define DH_     32
#define LEN_IN_ 14960
#define KDIM    256

#define MV_   119680   // N_BATCH * LEN_IN_
#define MQ_   20000    // N_BATCH * LQ_
#define NBMV  935      // MV_/128 row panels (exact)
#define NBMQ  157      // ceil(MQ_/128) row panels
#define NVB   1872     // value-GEMM block slots (8 xcd * 117 * 2, 2 idle)
#define NCB   960      // comb-GEMM block slots (8 xcd * 20 * 6)

// Fixed level geometry (matches SPATIAL in the reference)
__constant__ int c_w[4]     = {176, 88, 44, 22};
__constant__ int c_h[4]     = {64, 32, 16, 8};
__constant__ int c_start[4] = {0, 11264, 14080, 14784};

using bf16x8 = __attribute__((ext_vector_type(8))) short;
using f32x4  = __attribute__((ext_vector_type(4))) float;

// direct-to-LDS 16B staging (dest = wave-uniform base + lane*16)
#define GLDS16(g, l)                                                         \
    __builtin_amdgcn_global_load_lds(                                        \
        (const __attribute__((address_space(1))) void*)(g),                  \
        (__attribute__((address_space(3))) void*)(l), 16, 0, 0)

// v_dot2_f32_f16: acc += p.h[0]*w.h[0] + p.h[1]*w.h[1]  (f32 accumulate)
static __device__ inline float fdot2_u(unsigned int p, unsigned int w, float c) {
    float r;
    asm("v_dot2_f32_f16 %0, %1, %2, %3" : "=v"(r) : "v"(p), "v"(w), "v"(c));
    return r;
}

// Truncation-based split: v ~= hi + lo with |dropped| <= 2^-16 |v|.
static __device__ inline void split_bf16(float v, unsigned short& hi, unsigned short& lo) {
    unsigned int u = __float_as_uint(v);
    hi = (unsigned short)(u >> 16);
    float hif = __uint_as_float(u & 0xFFFF0000u);
    float l = v - hif;
    lo = (unsigned short)(__float_as_uint(l) >> 16);
}

// round-to-nearest-even f32 -> bf16
static __device__ inline unsigned short f2bf_rne(float v) {
    unsigned int u = __float_as_uint(v);
    u += 0x7FFFu + ((u >> 16) & 1u);
    return (unsigned short)(u >> 16);
}

// round-to-nearest-even f32 -> f16 (bit pattern)
static __device__ inline unsigned short f2h_rne(float v) {
    _Float16 h = (_Float16)v;
    return __builtin_bit_cast(unsigned short, h);
}

// ---------------------------------------------------------------------------
// One-shot weight preprocessing: transpose to [N][K] (k-contiguous) and split
// into bf16 hi/lo pairs. Wo (256x512) and Wa (256x256) concatenated -> 768 cols.
// (~1 MB of traffic; the big input casts happen inside gemm2's A staging.)
// ---------------------------------------------------------------------------
__global__ __launch_bounds__(256) void conv_weights(
    const float* __restrict__ Wv, const float* __restrict__ Wo,
    const float* __restrict__ Wa, const float* __restrict__ bo,
    const float* __restrict__ ba,
    unsigned short* __restrict__ Wv_hi, unsigned short* __restrict__ Wv_lo,
    unsigned short* __restrict__ Wc_hi, unsigned short* __restrict__ Wc_lo,
    float* __restrict__ bcomb)
{
    int id = blockIdx.x * 256 + threadIdx.x;
    if (id < 256 * 256) {                       // Wv -> Wv_t[n][k]
        int n = id >> 8, k = id & 255;
        unsigned short h, l;
        split_bf16(Wv[k * 256 + n], h, l);
        Wv_hi[id] = h; Wv_lo[id] = l;
    } else {                                    // [Wo | Wa] -> Wc_t[n][k]
        int id2 = id - 65536;
        if (id2 < 768 * 256) {
            int n = id2 >> 8, k = id2 & 255;
            float v = (n < 512) ? Wo[k * 512 + n] : Wa[k * 256 + (n - 512)];
            unsigned short h, l;
            split_bf16(v, h, l);
            Wc_hi[id2] = h; Wc_lo[id2] = l;
        }
    }
    if (id < 768) bcomb[id] = (id < 512) ? bo[id] : ba[id - 512];
}

// ---------------------------------------------------------------------------
// Stage-2: BOTH GEMMs in one dispatch by block-range concatenation.
//   bid <  NVB : value GEMM  input_flatten(f32) @ (Wvh+Wvl) -> f16 value
//   bid >= NVB : comb GEMM   query(f32)        @ (Wch+Wcl) -> f32 combq
// A path: f32 register-staged, in-register RNE f32->bf16, one ds_write_b128,
// *** 2-deep prefetch *** (issue tile kt+2 while computing kt): round-6's
// 1-deep gave only ~400cyc of cover vs ~900cyc HBM latency -> every K-step
// stalled. 2-deep covers ~2 full iterations. Index kt&1 is static after the
// full unroll (no scratch; verify WRITE_SIZE stays ~120 MB).
// B path: global_load_lds (unchanged).
// __launch_bounds__(512,4): 128-reg budget; ~60 VGPR + 32 AGPR fits, NO spill
// (round 5's (512,8) forced 64 and spilled 434 MB to scratch).
// ---------------------------------------------------------------------------
__global__ __launch_bounds__(512, 4) void gemm2(
    const float* __restrict__ Av,              // [MV_][256] f32 input_flatten
    const float* __restrict__ Aq,              // [MQ_][256] f32 query
    const unsigned short* __restrict__ Wvh, const unsigned short* __restrict__ Wvl,
    const unsigned short* __restrict__ Wch, const unsigned short* __restrict__ Wcl,
    const float* __restrict__ bv, const float* __restrict__ bc,
    float* __restrict__ Cq,                    // combq f32 (20000x768)
    unsigned short* __restrict__ Cv)           // value f16 (n,h,pix,dh)
{
    __shared__ __align__(16) unsigned short As [4096];  // [128][32]
    __shared__ __align__(16) unsigned short Bhs[4096];
    __shared__ __align__(16) unsigned short Bls[4096];

    const int tid = threadIdx.x;
    const int bid = blockIdx.x;
    const bool is_comb = (bid >= NVB);

    const float* A;
    const unsigned short *Bth, *Btl;
    const float* bias;
    int by, bx, M, N;
    if (is_comb) {
        // NVB % 8 == 0, so bid&7 == cid&7 (physical XCD residue preserved)
        int cid = bid - NVB;
        int xcd = cid & 7, j = cid >> 3;        // j in [0,120)
        by = xcd + 8 * (j / 6); bx = j % 6;
        if (by >= NBMQ) return;
        A = Aq; Bth = Wch; Btl = Wcl; bias = bc;
        M = MQ_; N = 768;
    } else {
        int xcd = bid & 7, j = bid >> 3;        // j in [0,234)
        by = xcd + 8 * (j >> 1); bx = j & 1;
        if (by >= NBMV) return;
        A = Av; Bth = Wvh; Btl = Wvl; bias = bv;
        M = MV_; N = 256;
    }

    const int row0 = by << 7, col0 = bx << 7;
    const int lane = tid & 63, wave = tid >> 6;
    const int wrow = (wave & 1) << 6, wcol = (wave >> 1) << 5;
    const int r16  = lane & 15, quad = lane >> 4;

    // staging: thread t -> row t>>2 (0..127), k-quarter t&3.
    const int srow = tid >> 2, skq = tid & 3;
    const int arow = min(row0 + srow, M - 1);   // clamp; epilogue masks
    const float* gA = A + (size_t)arow * KDIM + skq * 8;          // 32B/lane
    const unsigned short* gBh = Bth + (size_t)(col0 + srow) * KDIM + skq * 8;
    const unsigned short* gBl = Btl + (size_t)(col0 + srow) * KDIM + skq * 8;
    unsigned short* lBh = &Bhs[wave << 9];      // wave-uniform LDS bases
    unsigned short* lBl = &Bls[wave << 9];
    const int aoff = srow * 32 + skq * 8;       // A ds_write elem offset

    // prologue: 2-deep A prefetch (tiles 0 and 1)
    float4 pa[2][2];
#pragma unroll
    for (int s = 0; s < 2; ++s) {
        pa[s][0] = *(const float4*)(gA + s * 32);
        pa[s][1] = *(const float4*)(gA + s * 32 + 4);
    }

    f32x4 acc[4][2];
#pragma unroll
    for (int i = 0; i < 4; ++i)
#pragma unroll
        for (int j = 0; j < 2; ++j) acc[i][j] = (f32x4){0.f, 0.f, 0.f, 0.f};

#pragma unroll
    for (int kt = 0; kt < 8; ++kt) {
        const int cur = kt & 1;                 // static after full unroll

        // ---- B: direct to LDS (async) ----
        GLDS16(gBh + kt * 32, lBh);
        GLDS16(gBl + kt * 32, lBl);
        // ---- A: in-register RNE cvt + one b128 LDS write ----
        {
            bf16x8 hv;
            hv[0] = (short)f2bf_rne(pa[cur][0].x); hv[1] = (short)f2bf_rne(pa[cur][0].y);
            hv[2] = (short)f2bf_rne(pa[cur][0].z); hv[3] = (short)f2bf_rne(pa[cur][0].w);
            hv[4] = (short)f2bf_rne(pa[cur][1].x); hv[5] = (short)f2bf_rne(pa[cur][1].y);
            hv[6] = (short)f2bf_rne(pa[cur][1].z); hv[7] = (short)f2bf_rne(pa[cur][1].w);
            *(bf16x8*)&As[aoff] = hv;
        }
        __syncthreads();                        // drains glds + ds_write

        // ---- A prefetch for tile kt+2 (covered by ~2 full iterations) ----
        if (kt < 6) {
            pa[cur][0] = *(const float4*)(gA + (kt + 2) * 32);
            pa[cur][1] = *(const float4*)(gA + (kt + 2) * 32 + 4);
        }

        // ---- fragments + MFMA ----
        bf16x8 fbh[2], fbl[2], fa[4];
#pragma unroll
        for (int tn = 0; tn < 2; ++tn) {
            int n = wcol + tn * 16 + r16;
            fbh[tn] = *(const bf16x8*)&Bhs[n * 32 + (quad << 3)];
            fbl[tn] = *(const bf16x8*)&Bls[n * 32 + (quad << 3)];
        }
#pragma unroll
        for (int tm = 0; tm < 4; ++tm)
            fa[tm] = *(const bf16x8*)&As[(wrow + tm * 16 + r16) * 32 + (quad << 3)];
#pragma unroll
        for (int tm = 0; tm < 4; ++tm)
#pragma unroll
            for (int tn = 0; tn < 2; ++tn) {
                acc[tm][tn] = __builtin_amdgcn_mfma_f32_16x16x32_bf16(fa[tm], fbl[tn], acc[tm][tn], 0, 0, 0);
                acc[tm][tn] = __builtin_amdgcn_mfma_f32_16x16x32_bf16(fa[tm], fbh[tn], acc[tm][tn], 0, 0, 0);
            }
        __syncthreads();
    }

    // ---- epilogue: C/D layout col=lane&15, row=quad*4+reg ----
    float bvs[2];
#pragma unroll
    for (int tn = 0; tn < 2; ++tn) bvs[tn] = bias[col0 + wcol + tn * 16 + r16];
#pragma unroll
    for (int tm = 0; tm < 4; ++tm) {
#pragma unroll
        for (int i = 0; i < 4; ++i) {
            int row = row0 + wrow + tm * 16 + (quad << 2) + i;
            if (row < M) {
                if (is_comb) {
                    float* crow = Cq + (size_t)row * N + col0 + wcol + r16;
#pragma unroll
                    for (int tn = 0; tn < 2; ++tn)
                        crow[tn * 16] = acc[tm][tn][i] + bvs[tn];
                } else {
                    int n   = row / LEN_IN_;
                    int pix = row - n * LEN_IN_;
#pragma unroll
                    for (int tn = 0; tn < 2; ++tn) {
                        int col = col0 + wcol + tn * 16 + r16;
                        int h = col >> 5, dh = col & 31;
                        size_t addr = ((size_t)(n * NH_ + h) * LEN_IN_ + pix) * DH_ + dh;
                        Cv[addr] = f2h_rne(acc[tm][tn][i] + bvs[tn]);
                    }
                }
            }
        }
    }
}

// ---------------------------------------------------------------------------
// Fused softmax + loc + bilinear sampling, XCD-locality version.
// Block = one (n, head) value slice (957 KB) x 64 queries; blockIdx swizzled
// so all blocks of a slice run on one XCD -> slice lives in that XCD's L2.
//   grid = 2560: xcd = b&7, j = b>>3, slice = (j/40)*8 + xcd, chunk = j%40.
// Stage: 256 thr = (q_local, l) -> 16B descriptors (ushort4 idx + half4 w).
// Gather: 256 thr = (q_local, dhg); value is f16 so two corners fold into one
// v_dot2_f32_f16 per channel pair (v_perm_b32 packs per-channel corner pairs;
// weights consumed directly as the packed half2 descriptor words).
// ---------------------------------------------------------------------------
__global__ __launch_bounds__(256, 4) void ms_sample(
    const unsigned short* __restrict__ value,  // (n, 8, len_in, 32) f16
    const float* __restrict__ comb,            // (n*lq, 768): off(512) | logit(256)
    const float* __restrict__ ref_pts,         // (n*lq, 4, 2)
    float* __restrict__ out)                   // (n*lq, 256)
{
    __shared__ uint4 s_desc[64][33];

    const int b     = blockIdx.x;
    const int xcd   = b & 7;
    const int j     = b >> 3;
    const int slice = (j / 40) * 8 + xcd;      // 0..63
    const int chunk = j % 40;
    const int n     = slice >> 3, h = slice & 7;
    const int q0    = chunk * 64;
    const int tid   = threadIdx.x;

    { // ---- stage ----
        int ql = tid >> 2, l = tid & 3;
        int q  = q0 + ql;
        if (q < LQ_) {
            int nq = n * LQ_ + q;
            const float* row = comb + (size_t)nq * 768;

            float4 L0 = *(const float4*)&row[512 + h * 32 + l * 8];
            float4 L1 = *(const float4*)&row[512 + h * 32 + l * 8 + 4];
            float lg[8] = {L0.x, L0.y, L0.z, L0.w, L1.x, L1.y, L1.z, L1.w};
            float m = lg[0];
#pragma unroll
            for (int i = 1; i < 8; ++i) m = fmaxf(m, lg[i]);
            m = fmaxf(m, __shfl_xor(m, 1));
            m = fmaxf(m, __shfl_xor(m, 2));
            float e[8], s = 0.f;
#pragma unroll
            for (int i = 0; i < 8; ++i) { e[i] = __expf(lg[i] - m); s += e[i]; }
            s += __shfl_xor(s, 1);
            s += __shfl_xor(s, 2);
            float inv = 1.f / s;

            float4 R0 = *(const float4*)&ref_pts[(size_t)nq * 8];
            float4 R1 = *(const float4*)&ref_pts[(size_t)nq * 8 + 4];
            float rx[4] = {R0.x, R0.z, R1.x, R1.z};
            float ry[4] = {R0.y, R0.w, R1.y, R1.w};

            float off[16];
#pragma unroll
            for (int i = 0; i < 4; ++i)
                *(float4*)&off[i * 4] = *(const float4*)&row[h * 64 + l * 16 + i * 4];

            float wl = (float)c_w[l], hl = (float)c_h[l];
            int wli = c_w[l], hli = c_h[l], st = c_start[l];
#pragma unroll
            for (int p = 0; p < 8; ++p) {
                int z = p & 3;
                float a = e[p] * inv;
                float x = rx[z] * wl + off[p * 2 + 0] - 0.5f;
                float y = ry[z] * hl + off[p * 2 + 1] - 0.5f;
                float x0f = floorf(x), y0f = floorf(y);
                int   x0 = (int)x0f,  y0 = (int)y0f;
                float wx = x - x0f,   wy = y - y0f;
                unsigned short ix[4];
                float wt[4];
#pragma unroll
                for (int jj = 0; jj < 4; ++jj) {
                    int xi = x0 + (jj & 1);
                    int yi = y0 + (jj >> 1);
                    float w = ((jj & 1) ? wx : 1.f - wx) * ((jj >> 1) ? wy : 1.f - wy);
                    bool valid = (xi >= 0) && (xi < wli) && (yi >= 0) && (yi < hli);
                    int xc = min(max(xi, 0), wli - 1);
                    int yc = min(max(yi, 0), hli - 1);
                    ix[jj] = (unsigned short)(yc * wli + xc);
                    wt[jj] = valid ? a * w : 0.f;
                }
                uint4 d;
                d.x = (unsigned int)(st + ix[0]) | ((unsigned int)(st + ix[1]) << 16);
                d.y = (unsigned int)(st + ix[2]) | ((unsigned int)(st + ix[3]) << 16);
                __half2 h01 = __floats2half2_rn(wt[0], wt[1]);
                __half2 h23 = __floats2half2_rn(wt[2], wt[3]);
                d.z = *(unsigned int*)&h01;
                d.w = *(unsigned int*)&h23;
                s_desc[ql][l * 8 + p] = d;
            }
        }
    }
    __syncthreads();

    // ---- gather (value accesses confined to this block's (n,h) slice) ----
    int ql = tid >> 2, dhg = tid & 3;
    int q  = q0 + ql;
    if (q >= LQ_) return;
    int nq = n * LQ_ + q;
    const unsigned short* vb = value
        + ((size_t)(n * NH_ + h) * LEN_IN_) * DH_ + dhg * 8;

    float acc[8];
#pragma unroll
    for (int i = 0; i < 8; ++i) acc[i] = 0.f;

#pragma unroll 4
    for (int s = 0; s < 32; ++s) {
        uint4 d = s_desc[ql][s];
        int i0 = d.x & 0xFFFF, i1 = d.x >> 16;
        int i2 = d.y & 0xFFFF, i3 = d.y >> 16;
        uint4 v0 = *(const uint4*)(vb + i0 * DH_);
        uint4 v1 = *(const uint4*)(vb + i1 * DH_);
        uint4 v2 = *(const uint4*)(vb + i2 * DH_);
        uint4 v3 = *(const uint4*)(vb + i3 * DH_);
        // corners 0,1 -> weights d.z ; corners 2,3 -> weights d.w
        acc[0] = fdot2_u(__builtin_amdgcn_perm(v1.x, v0.x, 0x05040100u), d.z, acc[0]);
        acc[1] = fdot2_u(__builtin_amdgcn_perm(v1.x, v0.x, 0x07060302u), d.z, acc[1]);
        acc[2] = fdot2_u(__builtin_amdgcn_perm(v1.y, v0.y, 0x05040100u), d.z, acc[2]);
        acc[3] = fdot2_u(__builtin_amdgcn_perm(v1.y, v0.y, 0x07060302u), d.z, acc[3]);
        acc[4] = fdot2_u(__builtin_amdgcn_perm(v1.z, v0.z, 0x05040100u), d.z, acc[4]);
        acc[5] = fdot2_u(__builtin_amdgcn_perm(v1.z, v0.z, 0x07060302u), d.z, acc[5]);
        acc[6] = fdot2_u(__builtin_amdgcn_perm(v1.w, v0.w, 0x05040100u), d.z, acc[6]);
        acc[7] = fdot2_u(__builtin_amdgcn_perm(v1.w, v0.w, 0x07060302u), d.z, acc[7]);
        acc[0] = fdot2_u(__builtin_amdgcn_perm(v3.x, v2.x, 0x05040100u), d.w, acc[0]);
        acc[1] = fdot2_u(__builtin_amdgcn_perm(v3.x, v2.x, 0x07060302u), d.w, acc[1]);
        acc[2] = fdot2_u(__builtin_amdgcn_perm(v3.y, v2.y, 0x05040100u), d.w, acc[2]);
        acc[3] = fdot2_u(__builtin_amdgcn_perm(v3.y, v2.y, 0x07060302u), d.w, acc[3]);
        acc[4] = fdot2_u(__builtin_amdgcn_perm(v3.z, v2.z, 0x05040100u), d.w, acc[4]);
        acc[5] = fdot2_u(__builtin_amdgcn_perm(v3.z, v2.z, 0x07060302u), d.w, acc[5]);
        acc[6] = fdot2_u(__builtin_amdgcn_perm(v3.w, v2.w, 0x05040100u), d.w, acc[6]);
        acc[7] = fdot2_u(__builtin_amdgcn_perm(v3.w, v2.w, 0x07060302u), d.w, acc[7]);
    }

    float* op = out + (size_t)nq * 256 + h * 32 + dhg * 8;
    *(float4*)&op[0] = make_float4(acc[0], acc[1], acc[2], acc[3]);
    *(float4*)&op[4] = make_float4(acc[4], acc[5], acc[6], acc[7]);
}

// ---------------------------------------------------------------------------
extern "C" void kernel_launch(void* const* d_in, const int* in_sizes, int n_in,
                              void* d_out, int out_size, void* d_ws, size_t ws_size,
                              hipStream_t stream)
{
    const float* query         = (const float*)d_in[0];
    const float* ref_pts       = (const float*)d_in[2];
    const float* input_flatten = (const float*)d_in[3];
    const float* Wv            = (const float*)d_in[6];
    const float* bv            = (const float*)d_in[7];
    const float* Wo            = (const float*)d_in[8];
    const float* bo            = (const float*)d_in[9];
    const float* Wa            = (const float*)d_in[10];
    const float* ba            = (const float*)d_in[11];
    float* out = (float*)d_out;

    char* ws = (char*)d_ws;
    size_t o = 0;
    unsigned short* Wv_hi = (unsigned short*)(ws + o); o += 256 * 256 * 2;
    unsigned short* Wv_lo = (unsigned short*)(ws + o); o += 256 * 256 * 2;
    unsigned short* Wc_hi = (unsigned short*)(ws + o); o += 768 * 256 * 2;
    unsigned short* Wc_lo = (unsigned short*)(ws + o); o += 768 * 256 * 2;
    float*          bcomb = (float*)(ws + o);          o += 768 * 4;
    o = (o + 511) & ~(size_t)511;
    unsigned short* value = (unsigned short*)(ws + o); o += (size_t)119680 * 256 * 2;
    o = (o + 511) & ~(size_t)511;
    float* combq = (float*)(ws + o); o += (size_t)20000 * 768 * 4;

    // stage 1: weights only (~1 MB)
    hipLaunchKernelGGL(conv_weights, dim3(1024), dim3(256), 0, stream,
                       Wv, Wo, Wa, bo, ba, Wv_hi, Wv_lo, Wc_hi, Wc_lo, bcomb);
    // stage 2: both GEMMs, one dispatch; A cast folded into staging
    hipLaunchKernelGGL(gemm2, dim3(NVB + NCB), dim3(512), 0, stream,
                       input_flatten, query, Wv_hi, Wv_lo, Wc_hi, Wc_lo,
                       bv, bcomb, combq, value);
    // stage 3: fused softmax + loc + bilinear sample + weighted sum
    hipLaunchKernelGGL(ms_sample, dim3(2560), dim3(256), 0, stream,
                       value, combq, ref_pts, out);
}

// Round 8
// 333.699 us; speedup vs baseline: 1.5221x; 1.0215x over previous
//
#include <hip/hip_runtime.h>
#include <hip/hip_fp16.h>

#define N_BATCH 8
#define LQ_     2500
#define DM_     256
#define NH_     8
#define NL_     4
#define NP_     8
#define DH_     32
#define LEN_IN_ 14960
#define KDIM    256

#define MV_   119680   // N_BATCH * LEN_IN_
#define MQ_   20000    // N_BATCH * LQ_
#define NBMV  935      // MV_/128 row panels (exact)
#define NBMQ  157      // ceil(MQ_/128) row panels
#define NVB   1872     // value-GEMM block slots (8 xcd * 117 * 2, 2 idle)
#define NCB   960      // comb-GEMM block slots (8 xcd * 20 * 6)

// Fixed level geometry (matches SPATIAL in the reference)
__constant__ int c_w[4]     = {176, 88, 44, 22};
__constant__ int c_h[4]     = {64, 32, 16, 8};
__constant__ int c_start[4] = {0, 11264, 14080, 14784};

using bf16x8 = __attribute__((ext_vector_type(8))) short;
using f32x4  = __attribute__((ext_vector_type(4))) float;

// direct-to-LDS 16B staging (dest = wave-uniform base + lane*16)
#define GLDS16(g, l)                                                         \
    __builtin_amdgcn_global_load_lds(                                        \
        (const __attribute__((address_space(1))) void*)(g),                  \
        (__attribute__((address_space(3))) void*)(l), 16, 0, 0)

// v_dot2_f32_f16: acc += p.h[0]*w.h[0] + p.h[1]*w.h[1]  (f32 accumulate)
static __device__ inline float fdot2_u(unsigned int p, unsigned int w, float c) {
    float r;
    asm("v_dot2_f32_f16 %0, %1, %2, %3" : "=v"(r) : "v"(p), "v"(w), "v"(c));
    return r;
}

// Truncation-based split: v ~= hi + lo with |dropped| <= 2^-16 |v|.
static __device__ inline void split_bf16(float v, unsigned short& hi, unsigned short& lo) {
    unsigned int u = __float_as_uint(v);
    hi = (unsigned short)(u >> 16);
    float hif = __uint_as_float(u & 0xFFFF0000u);
    float l = v - hif;
    lo = (unsigned short)(__float_as_uint(l) >> 16);
}

// round-to-nearest-even f32 -> bf16
static __device__ inline unsigned short f2bf_rne(float v) {
    unsigned int u = __float_as_uint(v);
    u += 0x7FFFu + ((u >> 16) & 1u);
    return (unsigned short)(u >> 16);
}

// round-to-nearest-even f32 -> f16 (bit pattern)
static __device__ inline unsigned short f2h_rne(float v) {
    _Float16 h = (_Float16)v;
    return __builtin_bit_cast(unsigned short, h);
}

static __device__ inline bf16x8 cvt8_rne(float4 a, float4 b) {
    bf16x8 hv;
    hv[0] = (short)f2bf_rne(a.x); hv[1] = (short)f2bf_rne(a.y);
    hv[2] = (short)f2bf_rne(a.z); hv[3] = (short)f2bf_rne(a.w);
    hv[4] = (short)f2bf_rne(b.x); hv[5] = (short)f2bf_rne(b.y);
    hv[6] = (short)f2bf_rne(b.z); hv[7] = (short)f2bf_rne(b.w);
    return hv;
}

// ---------------------------------------------------------------------------
// One-shot weight preprocessing: transpose to [N][K] (k-contiguous) and split
// into bf16 hi/lo pairs. Wo (256x512) and Wa (256x256) concatenated -> 768 cols.
// ---------------------------------------------------------------------------
__global__ __launch_bounds__(256) void conv_weights(
    const float* __restrict__ Wv, const float* __restrict__ Wo,
    const float* __restrict__ Wa, const float* __restrict__ bo,
    const float* __restrict__ ba,
    unsigned short* __restrict__ Wv_hi, unsigned short* __restrict__ Wv_lo,
    unsigned short* __restrict__ Wc_hi, unsigned short* __restrict__ Wc_lo,
    float* __restrict__ bcomb)
{
    int id = blockIdx.x * 256 + threadIdx.x;
    if (id < 256 * 256) {                       // Wv -> Wv_t[n][k]
        int n = id >> 8, k = id & 255;
        unsigned short h, l;
        split_bf16(Wv[k * 256 + n], h, l);
        Wv_hi[id] = h; Wv_lo[id] = l;
    } else {                                    // [Wo | Wa] -> Wc_t[n][k]
        int id2 = id - 65536;
        if (id2 < 768 * 256) {
            int n = id2 >> 8, k = id2 & 255;
            float v = (n < 512) ? Wo[k * 512 + n] : Wa[k * 256 + (n - 512)];
            unsigned short h, l;
            split_bf16(v, h, l);
            Wc_hi[id2] = h; Wc_lo[id2] = l;
        }
    }
    if (id < 768) bcomb[id] = (id < 512) ? bo[id] : ba[id - 512];
}

// ---------------------------------------------------------------------------
// Stage-2: BOTH GEMMs in one dispatch by block-range concatenation.
//   bid <  NVB : value GEMM  input_flatten(f32) @ (Wvh+Wvl) -> f16 value
//   bid >= NVB : comb GEMM   query(f32)        @ (Wch+Wcl) -> f32 combq
// *** Double-buffered LDS, ONE barrier per K-step *** (rounds 6/7 issued the
// B glds immediately before __syncthreads -> full B-load latency exposed
// every step, twice-bracketed by 16 barriers/block; the 2-deep A prefetch
// couldn't help because A was never the exposed load).
// Per step kt: issue GLDS B(kt+1)->buf[nxt] + ds_write A(kt+1)->As[nxt]
// FIRST, then fragments+MFMA from buf[cur], then one __syncthreads (drains
// glds that had the whole MFMA phase to land). A regs stay 2-deep.
// LDS 2 x 24 KB = 48 KB; occupancy unchanged (128-reg budget already caps
// at 2 blocks/CU). All buffer indices static after full unroll.
// ---------------------------------------------------------------------------
__global__ __launch_bounds__(512, 4) void gemm2(
    const float* __restrict__ Av,              // [MV_][256] f32 input_flatten
    const float* __restrict__ Aq,              // [MQ_][256] f32 query
    const unsigned short* __restrict__ Wvh, const unsigned short* __restrict__ Wvl,
    const unsigned short* __restrict__ Wch, const unsigned short* __restrict__ Wcl,
    const float* __restrict__ bv, const float* __restrict__ bc,
    float* __restrict__ Cq,                    // combq f32 (20000x768)
    unsigned short* __restrict__ Cv)           // value f16 (n,h,pix,dh)
{
    __shared__ __align__(16) unsigned short As [2][4096];  // [128][32] x2
    __shared__ __align__(16) unsigned short Bhs[2][4096];
    __shared__ __align__(16) unsigned short Bls[2][4096];

    const int tid = threadIdx.x;
    const int bid = blockIdx.x;
    const bool is_comb = (bid >= NVB);

    const float* A;
    const unsigned short *Bth, *Btl;
    const float* bias;
    int by, bx, M, N;
    if (is_comb) {
        // NVB % 8 == 0, so bid&7 == cid&7 (physical XCD residue preserved)
        int cid = bid - NVB;
        int xcd = cid & 7, j = cid >> 3;        // j in [0,120)
        by = xcd + 8 * (j / 6); bx = j % 6;
        if (by >= NBMQ) return;
        A = Aq; Bth = Wch; Btl = Wcl; bias = bc;
        M = MQ_; N = 768;
    } else {
        int xcd = bid & 7, j = bid >> 3;        // j in [0,234)
        by = xcd + 8 * (j >> 1); bx = j & 1;
        if (by >= NBMV) return;
        A = Av; Bth = Wvh; Btl = Wvl; bias = bv;
        M = MV_; N = 256;
    }

    const int row0 = by << 7, col0 = bx << 7;
    const int lane = tid & 63, wave = tid >> 6;
    const int wrow = (wave & 1) << 6, wcol = (wave >> 1) << 5;
    const int r16  = lane & 15, quad = lane >> 4;

    // staging: thread t -> row t>>2 (0..127), k-quarter t&3.
    const int srow = tid >> 2, skq = tid & 3;
    const int arow = min(row0 + srow, M - 1);   // clamp; epilogue masks
    const float* gA = A + (size_t)arow * KDIM + skq * 8;          // 32B/lane
    const unsigned short* gBh = Bth + (size_t)(col0 + srow) * KDIM + skq * 8;
    const unsigned short* gBl = Btl + (size_t)(col0 + srow) * KDIM + skq * 8;
    const int lbase = wave << 9;                // wave-uniform LDS elem base
    const int aoff  = srow * 32 + skq * 8;      // A ds_write elem offset

    // ---- prologue: tile 0 staged, tiles 0/1 A-regs resident ----
    GLDS16(gBh, &Bhs[0][lbase]);
    GLDS16(gBl, &Bls[0][lbase]);
    float4 pa[2][2];
#pragma unroll
    for (int s = 0; s < 2; ++s) {
        pa[s][0] = *(const float4*)(gA + s * 32);
        pa[s][1] = *(const float4*)(gA + s * 32 + 4);
    }
    *(bf16x8*)&As[0][aoff] = cvt8_rne(pa[0][0], pa[0][1]);   // A(0)
    __syncthreads();                            // tile 0 ready

    f32x4 acc[4][2];
#pragma unroll
    for (int i = 0; i < 4; ++i)
#pragma unroll
        for (int j = 0; j < 2; ++j) acc[i][j] = (f32x4){0.f, 0.f, 0.f, 0.f};

#pragma unroll
    for (int kt = 0; kt < 8; ++kt) {
        const int cur = kt & 1, nxt = cur ^ 1;  // static after full unroll

        // ---- stage tile kt+1 into buf[nxt] (covered by MFMA phase) ----
        if (kt < 7) {
            GLDS16(gBh + (kt + 1) * 32, &Bhs[nxt][lbase]);
            GLDS16(gBl + (kt + 1) * 32, &Bls[nxt][lbase]);
            // A(kt+1): cvt + ds_write from pa[(kt+1)&1]
            *(bf16x8*)&As[nxt][aoff] =
                cvt8_rne(pa[nxt][0], pa[nxt][1]);    // (kt+1)&1 == nxt
        }
        // ---- A-reg prefetch for tile kt+2 (consumed next step) ----
        if (kt < 6) {
            pa[cur][0] = *(const float4*)(gA + (kt + 2) * 32);
            pa[cur][1] = *(const float4*)(gA + (kt + 2) * 32 + 4);
        }

        // ---- fragments + MFMA from buf[cur] ----
        bf16x8 fbh[2], fbl[2], fa[4];
#pragma unroll
        for (int tn = 0; tn < 2; ++tn) {
            int n = wcol + tn * 16 + r16;
            fbh[tn] = *(const bf16x8*)&Bhs[cur][n * 32 + (quad << 3)];
            fbl[tn] = *(const bf16x8*)&Bls[cur][n * 32 + (quad << 3)];
        }
#pragma unroll
        for (int tm = 0; tm < 4; ++tm)
            fa[tm] = *(const bf16x8*)&As[cur][(wrow + tm * 16 + r16) * 32 + (quad << 3)];
#pragma unroll
        for (int tm = 0; tm < 4; ++tm)
#pragma unroll
            for (int tn = 0; tn < 2; ++tn) {
                acc[tm][tn] = __builtin_amdgcn_mfma_f32_16x16x32_bf16(fa[tm], fbl[tn], acc[tm][tn], 0, 0, 0);
                acc[tm][tn] = __builtin_amdgcn_mfma_f32_16x16x32_bf16(fa[tm], fbh[tn], acc[tm][tn], 0, 0, 0);
            }

        // ---- one barrier: publishes tile kt+1, retires buf[cur] readers ----
        __syncthreads();
    }

    // ---- epilogue: C/D layout col=lane&15, row=quad*4+reg ----
    float bvs[2];
#pragma unroll
    for (int tn = 0; tn < 2; ++tn) bvs[tn] = bias[col0 + wcol + tn * 16 + r16];
#pragma unroll
    for (int tm = 0; tm < 4; ++tm) {
#pragma unroll
        for (int i = 0; i < 4; ++i) {
            int row = row0 + wrow + tm * 16 + (quad << 2) + i;
            if (row < M) {
                if (is_comb) {
                    float* crow = Cq + (size_t)row * N + col0 + wcol + r16;
#pragma unroll
                    for (int tn = 0; tn < 2; ++tn)
                        crow[tn * 16] = acc[tm][tn][i] + bvs[tn];
                } else {
                    int n   = row / LEN_IN_;
                    int pix = row - n * LEN_IN_;
#pragma unroll
                    for (int tn = 0; tn < 2; ++tn) {
                        int col = col0 + wcol + tn * 16 + r16;
                        int h = col >> 5, dh = col & 31;
                        size_t addr = ((size_t)(n * NH_ + h) * LEN_IN_ + pix) * DH_ + dh;
                        Cv[addr] = f2h_rne(acc[tm][tn][i] + bvs[tn]);
                    }
                }
            }
        }
    }
}

// ---------------------------------------------------------------------------
// Fused softmax + loc + bilinear sampling, XCD-locality version.
// Block = one (n, head) value slice (957 KB) x 64 queries; blockIdx swizzled
// so all blocks of a slice run on one XCD -> slice lives in that XCD's L2.
//   grid = 2560: xcd = b&7, j = b>>3, slice = (j/40)*8 + xcd, chunk = j%40.
// Stage: 256 thr = (q_local, l) -> 16B descriptors (ushort4 idx + half4 w).
// Gather: 256 thr = (q_local, dhg); value is f16 so two corners fold into one
// v_dot2_f32_f16 per channel pair (v_perm_b32 packs per-channel corner pairs;
// weights consumed directly as the packed half2 descriptor words).
// ---------------------------------------------------------------------------
__global__ __launch_bounds__(256, 4) void ms_sample(
    const unsigned short* __restrict__ value,  // (n, 8, len_in, 32) f16
    const float* __restrict__ comb,            // (n*lq, 768): off(512) | logit(256)
    const float* __restrict__ ref_pts,         // (n*lq, 4, 2)
    float* __restrict__ out)                   // (n*lq, 256)
{
    __shared__ uint4 s_desc[64][33];

    const int b     = blockIdx.x;
    const int xcd   = b & 7;
    const int j     = b >> 3;
    const int slice = (j / 40) * 8 + xcd;      // 0..63
    const int chunk = j % 40;
    const int n     = slice >> 3, h = slice & 7;
    const int q0    = chunk * 64;
    const int tid   = threadIdx.x;

    { // ---- stage ----
        int ql = tid >> 2, l = tid & 3;
        int q  = q0 + ql;
        if (q < LQ_) {
            int nq = n * LQ_ + q;
            const float* row = comb + (size_t)nq * 768;

            float4 L0 = *(const float4*)&row[512 + h * 32 + l * 8];
            float4 L1 = *(const float4*)&row[512 + h * 32 + l * 8 + 4];
            float lg[8] = {L0.x, L0.y, L0.z, L0.w, L1.x, L1.y, L1.z, L1.w};
            float m = lg[0];
#pragma unroll
            for (int i = 1; i < 8; ++i) m = fmaxf(m, lg[i]);
            m = fmaxf(m, __shfl_xor(m, 1));
            m = fmaxf(m, __shfl_xor(m, 2));
            float e[8], s = 0.f;
#pragma unroll
            for (int i = 0; i < 8; ++i) { e[i] = __expf(lg[i] - m); s += e[i]; }
            s += __shfl_xor(s, 1);
            s += __shfl_xor(s, 2);
            float inv = 1.f / s;

            float4 R0 = *(const float4*)&ref_pts[(size_t)nq * 8];
            float4 R1 = *(const float4*)&ref_pts[(size_t)nq * 8 + 4];
            float rx[4] = {R0.x, R0.z, R1.x, R1.z};
            float ry[4] = {R0.y, R0.w, R1.y, R1.w};

            float off[16];
#pragma unroll
            for (int i = 0; i < 4; ++i)
                *(float4*)&off[i * 4] = *(const float4*)&row[h * 64 + l * 16 + i * 4];

            float wl = (float)c_w[l], hl = (float)c_h[l];
            int wli = c_w[l], hli = c_h[l], st = c_start[l];
#pragma unroll
            for (int p = 0; p < 8; ++p) {
                int z = p & 3;
                float a = e[p] * inv;
                float x = rx[z] * wl + off[p * 2 + 0] - 0.5f;
                float y = ry[z] * hl + off[p * 2 + 1] - 0.5f;
                float x0f = floorf(x), y0f = floorf(y);
                int   x0 = (int)x0f,  y0 = (int)y0f;
                float wx = x - x0f,   wy = y - y0f;
                unsigned short ix[4];
                float wt[4];
#pragma unroll
                for (int jj = 0; jj < 4; ++jj) {
                    int xi = x0 + (jj & 1);
                    int yi = y0 + (jj >> 1);
                    float w = ((jj & 1) ? wx : 1.f - wx) * ((jj >> 1) ? wy : 1.f - wy);
                    bool valid = (xi >= 0) && (xi < wli) && (yi >= 0) && (yi < hli);
                    int xc = min(max(xi, 0), wli - 1);
                    int yc = min(max(yi, 0), hli - 1);
                    ix[jj] = (unsigned short)(yc * wli + xc);
                    wt[jj] = valid ? a * w : 0.f;
                }
                uint4 d;
                d.x = (unsigned int)(st + ix[0]) | ((unsigned int)(st + ix[1]) << 16);
                d.y = (unsigned int)(st + ix[2]) | ((unsigned int)(st + ix[3]) << 16);
                __half2 h01 = __floats2half2_rn(wt[0], wt[1]);
                __half2 h23 = __floats2half2_rn(wt[2], wt[3]);
                d.z = *(unsigned int*)&h01;
                d.w = *(unsigned int*)&h23;
                s_desc[ql][l * 8 + p] = d;
            }
        }
    }
    __syncthreads();

    // ---- gather (value accesses confined to this block's (n,h) slice) ----
    int ql = tid >> 2, dhg = tid & 3;
    int q  = q0 + ql;
    if (q >= LQ_) return;
    int nq = n * LQ_ + q;
    const unsigned short* vb = value
        + ((size_t)(n * NH_ + h) * LEN_IN_) * DH_ + dhg * 8;

    float acc[8];
#pragma unroll
    for (int i = 0; i < 8; ++i) acc[i] = 0.f;

#pragma unroll 4
    for (int s = 0; s < 32; ++s) {
        uint4 d = s_desc[ql][s];
        int i0 = d.x & 0xFFFF, i1 = d.x >> 16;
        int i2 = d.y & 0xFFFF, i3 = d.y >> 16;
        uint4 v0 = *(const uint4*)(vb + i0 * DH_);
        uint4 v1 = *(const uint4*)(vb + i1 * DH_);
        uint4 v2 = *(const uint4*)(vb + i2 * DH_);
        uint4 v3 = *(const uint4*)(vb + i3 * DH_);
        // corners 0,1 -> weights d.z ; corners 2,3 -> weights d.w
        acc[0] = fdot2_u(__builtin_amdgcn_perm(v1.x, v0.x, 0x05040100u), d.z, acc[0]);
        acc[1] = fdot2_u(__builtin_amdgcn_perm(v1.x, v0.x, 0x07060302u), d.z, acc[1]);
        acc[2] = fdot2_u(__builtin_amdgcn_perm(v1.y, v0.y, 0x05040100u), d.z, acc[2]);
        acc[3] = fdot2_u(__builtin_amdgcn_perm(v1.y, v0.y, 0x07060302u), d.z, acc[3]);
        acc[4] = fdot2_u(__builtin_amdgcn_perm(v1.z, v0.z, 0x05040100u), d.z, acc[4]);
        acc[5] = fdot2_u(__builtin_amdgcn_perm(v1.z, v0.z, 0x07060302u), d.z, acc[5]);
        acc[6] = fdot2_u(__builtin_amdgcn_perm(v1.w, v0.w, 0x05040100u), d.z, acc[6]);
        acc[7] = fdot2_u(__builtin_amdgcn_perm(v1.w, v0.w, 0x07060302u), d.z, acc[7]);
        acc[0] = fdot2_u(__builtin_amdgcn_perm(v3.x, v2.x, 0x05040100u), d.w, acc[0]);
        acc[1] = fdot2_u(__builtin_amdgcn_perm(v3.x, v2.x, 0x07060302u), d.w, acc[1]);
        acc[2] = fdot2_u(__builtin_amdgcn_perm(v3.y, v2.y, 0x05040100u), d.w, acc[2]);
        acc[3] = fdot2_u(__builtin_amdgcn_perm(v3.y, v2.y, 0x07060302u), d.w, acc[3]);
        acc[4] = fdot2_u(__builtin_amdgcn_perm(v3.z, v2.z, 0x05040100u), d.w, acc[4]);
        acc[5] = fdot2_u(__builtin_amdgcn_perm(v3.z, v2.z, 0x07060302u), d.w, acc[5]);
        acc[6] = fdot2_u(__builtin_amdgcn_perm(v3.w, v2.w, 0x05040100u), d.w, acc[6]);
        acc[7] = fdot2_u(__builtin_amdgcn_perm(v3.w, v2.w, 0x07060302u), d.w, acc[7]);
    }

    float* op = out + (size_t)nq * 256 + h * 32 + dhg * 8;
    *(float4*)&op[0] = make_float4(acc[0], acc[1], acc[2], acc[3]);
    *(float4*)&op[4] = make_float4(acc[4], acc[5], acc[6], acc[7]);
}

// ---------------------------------------------------------------------------
extern "C" void kernel_launch(void* const* d_in, const int* in_sizes, int n_in,
                              void* d_out, int out_size, void* d_ws, size_t ws_size,
                              hipStream_t stream)
{
    const float* query         = (const float*)d_in[0];
    const float* ref_pts       = (const float*)d_in[2];
    const float* input_flatten = (const float*)d_in[3];
    const float* Wv            = (const float*)d_in[6];
    const float* bv            = (const float*)d_in[7];
    const float* Wo            = (const float*)d_in[8];
    const float* bo            = (const float*)d_in[9];
    const float* Wa            = (const float*)d_in[10];
    const float* ba            = (const float*)d_in[11];
    float* out = (float*)d_out;

    char* ws = (char*)d_ws;
    size_t o = 0;
    unsigned short* Wv_hi = (unsigned short*)(ws + o); o += 256 * 256 * 2;
    unsigned short* Wv_lo = (unsigned short*)(ws + o); o += 256 * 256 * 2;
    unsigned short* Wc_hi = (unsigned short*)(ws + o); o += 768 * 256 * 2;
    unsigned short* Wc_lo = (unsigned short*)(ws + o); o += 768 * 256 * 2;
    float*          bcomb = (float*)(ws + o);          o += 768 * 4;
    o = (o + 511) & ~(size_t)511;
    unsigned short* value = (unsigned short*)(ws + o); o += (size_t)119680 * 256 * 2;
    o = (o + 511) & ~(size_t)511;
    float* combq = (float*)(ws + o); o += (size_t)20000 * 768 * 4;

    // stage 1: weights only (~1 MB)
    hipLaunchKernelGGL(conv_weights, dim3(1024), dim3(256), 0, stream,
                       Wv, Wo, Wa, bo, ba, Wv_hi, Wv_lo, Wc_hi, Wc_lo, bcomb);
    // stage 2: both GEMMs, one dispatch; A cast folded into staging
    hipLaunchKernelGGL(gemm2, dim3(NVB + NCB), dim3(512), 0, stream,
                       input_flatten, query, Wv_hi, Wv_lo, Wc_hi, Wc_lo,
                       bv, bcomb, combq, value);
    // stage 3: fused softmax + loc + bilinear sample + weighted sum
    hipLaunchKernelGGL(ms_sample, dim3(2560), dim3(256), 0, stream,
                       value, combq, ref_pts, out);
}